// Round 3
// baseline (666.531 us; speedup 1.0000x reference)
//
#include <hip/hip_runtime.h>
#include <stdint.h>

#define Hh 8
#define Bb 32
#define Tt 512
#define Ee 512
#define Nn 16384            // Bb*Tt
#define GAMMA_ 1.5f
#define BN_EPS_ 1e-5f

typedef _Float16 f16x4 __attribute__((ext_vector_type(4)));
typedef _Float16 f16x8 __attribute__((ext_vector_type(8)));
typedef float    f32x4 __attribute__((ext_vector_type(4)));

__device__ __forceinline__ void async_ld16(void* lds, const void* g) {
    __builtin_amdgcn_global_load_lds(
        (const __attribute__((address_space(1))) void*)g,
        (__attribute__((address_space(3))) void*)lds, 16, 0, 0);
}

// Full-wave (64-lane) f32 sum via DPP (pure VALU, no DS pipe).
__device__ __forceinline__ float dpp_sum64(float v) {
    int t;
    t = __builtin_amdgcn_update_dpp(0, __float_as_int(v), 0x111, 0xf, 0xf, true);
    v += __int_as_float(t);
    t = __builtin_amdgcn_update_dpp(0, __float_as_int(v), 0x112, 0xf, 0xf, true);
    v += __int_as_float(t);
    t = __builtin_amdgcn_update_dpp(0, __float_as_int(v), 0x114, 0xf, 0xf, true);
    v += __int_as_float(t);
    t = __builtin_amdgcn_update_dpp(0, __float_as_int(v), 0x118, 0xf, 0xf, true);
    v += __int_as_float(t);
    t = __builtin_amdgcn_update_dpp(0, __float_as_int(v), 0x142, 0xf, 0xf, true);
    v += __int_as_float(t);
    t = __builtin_amdgcn_update_dpp(0, __float_as_int(v), 0x143, 0xf, 0xf, true);
    v += __int_as_float(t);
    return __int_as_float(__builtin_amdgcn_readlane(__float_as_int(v), 63));
}

// Full-wave f32 max via DPP. old=src + bound_ctrl=false => invalid lanes are
// identity under fmax (no 0.0 injection; safe for all-negative inputs).
__device__ __forceinline__ float dpp_max64(float v) {
    int t;
    t = __builtin_amdgcn_update_dpp(__float_as_int(v), __float_as_int(v), 0x111, 0xf, 0xf, false);
    v = fmaxf(v, __int_as_float(t));
    t = __builtin_amdgcn_update_dpp(__float_as_int(v), __float_as_int(v), 0x112, 0xf, 0xf, false);
    v = fmaxf(v, __int_as_float(t));
    t = __builtin_amdgcn_update_dpp(__float_as_int(v), __float_as_int(v), 0x114, 0xf, 0xf, false);
    v = fmaxf(v, __int_as_float(t));
    t = __builtin_amdgcn_update_dpp(__float_as_int(v), __float_as_int(v), 0x118, 0xf, 0xf, false);
    v = fmaxf(v, __int_as_float(t));
    t = __builtin_amdgcn_update_dpp(__float_as_int(v), __float_as_int(v), 0x142, 0xf, 0xf, false);
    v = fmaxf(v, __int_as_float(t));
    t = __builtin_amdgcn_update_dpp(__float_as_int(v), __float_as_int(v), 0x143, 0xf, 0xf, false);
    v = fmaxf(v, __int_as_float(t));
    return __int_as_float(__builtin_amdgcn_readlane(__float_as_int(v), 63));
}

// ---------------- K0: fp32 -> f16 convert (x then W, contiguous) ----------------
__global__ __launch_bounds__(256) void cvt_kernel(const float* __restrict__ x,
                                                  const float* __restrict__ W,
                                                  _Float16* __restrict__ xh,
                                                  _Float16* __restrict__ wh) {
    const int NX = Bb * Tt * Ee;               // 8388608, divisible by 4
    int i = (blockIdx.x * 256 + threadIdx.x) * 4;
    if (i < NX) {
        float4 v = *(const float4*)(x + i);
        f16x4 o = {(_Float16)v.x, (_Float16)v.y, (_Float16)v.z, (_Float16)v.w};
        *(f16x4*)(xh + i) = o;
    } else {
        int j = i - NX;                        // 0 .. 2097151
        float4 v = *(const float4*)(W + j);
        f16x4 o = {(_Float16)v.x, (_Float16)v.y, (_Float16)v.z, (_Float16)v.w};
        *(f16x4*)(wh + j) = o;
    }
}

// ---------------- K1: batched NT GEMM, 256x256 tiles, f16 MFMA ------------------
// T4 counted-vmcnt deep pipeline: 4 LDS buffers (128 KB), stage depth 3,
// inline-asm s_waitcnt vmcnt(8) + raw s_barrier. Loads stay in flight across
// barriers (never drain to 0 in the main loop); 3-step lead (~900+ cy at 2
// waves/SIMD) covers HBM latency. Race-safety: stage for step s+3 writes the
// buffer last read at step s-1; those reads completed before this step's
// barrier (each wave's MFMAs consumed them in program order). vmcnt(8) before
// the barrier retires this step's 4 loads per wave; barrier then guarantees
// ALL waves' loads for this buffer have landed.
__global__ __launch_bounds__(512, 2) void gemm_kernel(const _Float16* __restrict__ A,
                                                      const _Float16* __restrict__ Bm,
                                                      _Float16* __restrict__ C,
                                                      float* __restrict__ sums,
                                                      float* __restrict__ sumsq) {
    __shared__ alignas(16) _Float16 As[4][256 * 32];   // 4 x 16 KB
    __shared__ alignas(16) _Float16 Bs[4][256 * 32];   // 4 x 16 KB
    const int id  = blockIdx.x;                // 0..1023
    const int h   = id >> 7;
    const int rem = id & 127;
    const int mb  = (rem >> 1) * 256;          // 64 row-blocks
    const int nb  = (rem & 1) * 256;           // 2 col-blocks

    const int t    = threadIdx.x;              // 0..511
    const int lane = t & 63;
    const int w    = t >> 6;                   // 0..7
    const int wrow = (w >> 2) * 128;           // 0,128
    const int wcol = (w & 3) * 64;             // 0,64,128,192
    const int quad = lane >> 4;
    const int l16  = lane & 15;

    // staging: thread t fills LDS chunks t and t+512 (rows t>>2 and 128+(t>>2),
    // slot t&3). Global k-chunk kc = (slot - (row>>1)) & 3; identical for both
    // chunks since +128 rows ≡ 0 mod 4 after >>1.
    const int kc = ((t & 3) - ((t >> 3) & 3)) & 3;
    const _Float16* Ap = A + (size_t)(mb + (t >> 2)) * Ee + kc * 8;
    const _Float16* Bp = Bm + (size_t)h * Ee * Ee + (size_t)(nb + (t >> 2)) * Ee + kc * 8;

    f32x4 acc[8][4] = {};

    // prologue: stage K-steps 0,1,2 into buffers 0,1,2 (12 loads/wave in flight)
#pragma unroll
    for (int s = 0; s < 3; ++s) {
        const _Float16* Aps = Ap + s * 32;
        const _Float16* Bps = Bp + s * 32;
        async_ld16(&As[s][t * 8],        Aps);
        async_ld16(&As[s][4096 + t * 8], Aps + 128 * Ee);
        async_ld16(&Bs[s][t * 8],        Bps);
        async_ld16(&Bs[s][4096 + t * 8], Bps + 128 * Ee);
    }

    // reader slot: chunk `quad` of row R lives at slot (quad+(R>>1))&3;
    // (R>>1)&3 == (l16>>1)&3 for all wrow/wcol/mt/nt used here.
    const int so = ((quad + (l16 >> 1)) & 3) * 8;

#pragma unroll 1
    for (int s = 0; s < 16; ++s) {             // 16 K-steps of 32
        // retire this step's 4 loads; keep later stages in flight (never 0
        // mid-loop). Tail: s=14 has only 2 stages outstanding, s=15 one.
        if (s < 14)       asm volatile("s_waitcnt vmcnt(8)" ::: "memory");
        else if (s == 14) asm volatile("s_waitcnt vmcnt(4)" ::: "memory");
        else              asm volatile("s_waitcnt vmcnt(0)" ::: "memory");
        __builtin_amdgcn_s_barrier();
        asm volatile("" ::: "memory");         // compiler fence: no LDS op crosses

        if (s + 3 < 16) {                      // stage step s+3 into buf (s+3)&3
            const int b = (s + 3) & 3;
            const _Float16* Aps = Ap + (s + 3) * 32;
            const _Float16* Bps = Bp + (s + 3) * 32;
            async_ld16(&As[b][t * 8],        Aps);
            async_ld16(&As[b][4096 + t * 8], Aps + 128 * Ee);
            async_ld16(&Bs[b][t * 8],        Bps);
            async_ld16(&Bs[b][4096 + t * 8], Bps + 128 * Ee);
        }

        const int c = s & 3;
        f16x8 b8[4];
#pragma unroll
        for (int nt = 0; nt < 4; ++nt)
            b8[nt] = *(const f16x8*)(&Bs[c][(wcol + nt * 16 + l16) * 32 + so]);
#pragma unroll
        for (int mt = 0; mt < 8; ++mt) {
            f16x8 a8 = *(const f16x8*)(&As[c][(wrow + mt * 16 + l16) * 32 + so]);
#pragma unroll
            for (int nt = 0; nt < 4; ++nt)
                acc[mt][nt] = __builtin_amdgcn_mfma_f32_16x16x32_f16(a8, b8[nt], acc[mt][nt], 0, 0, 0);
        }
    }

    // BN partial sums: reduce over rows (mt,r) then across quads (lanes xor 16,32)
#pragma unroll
    for (int nt = 0; nt < 4; ++nt) {
        float sv = 0.f, ss = 0.f;
#pragma unroll
        for (int mt = 0; mt < 8; ++mt)
#pragma unroll
            for (int rr = 0; rr < 4; ++rr) { float v = acc[mt][nt][rr]; sv += v; ss += v * v; }
        sv += __shfl_xor(sv, 16, 64); sv += __shfl_xor(sv, 32, 64);
        ss += __shfl_xor(ss, 16, 64); ss += __shfl_xor(ss, 32, 64);
        if (quad == 0) {
            int col = nb + wcol + nt * 16 + l16;
            atomicAdd(&sums[h * Ee + col], sv);
            atomicAdd(&sumsq[h * Ee + col], ss);
        }
    }

    // store C (f16): C/D layout col=lane&15, row=quad*4+reg
    _Float16* Cp = C + (size_t)h * Nn * Ee;
#pragma unroll
    for (int mt = 0; mt < 8; ++mt)
#pragma unroll
        for (int rr = 0; rr < 4; ++rr) {
            int row = mb + wrow + mt * 16 + quad * 4 + rr;
            size_t off = (size_t)row * Ee + nb + wcol + l16;
#pragma unroll
            for (int nt = 0; nt < 4; ++nt)
                Cp[off + nt * 16] = (_Float16)acc[mt][nt][rr];
        }
}

// ---------------- K2: finalize BN stats into affine coefs -----------------------
__global__ __launch_bounds__(256) void stats_kernel(const float* __restrict__ sums,
                                                    const float* __restrict__ sumsq,
                                                    const float* __restrict__ bnw,
                                                    const float* __restrict__ bnb,
                                                    float* __restrict__ cA,
                                                    float* __restrict__ cB) {
    int i = blockIdx.x * 256 + threadIdx.x;    // 0..4095
    float mean = sums[i] * (1.0f / Nn);
    float var  = sumsq[i] * (1.0f / Nn) - mean * mean;
    float inv  = rsqrtf(var + BN_EPS_);
    float a    = bnw[i] * inv;
    cA[i] = a;
    cB[i] = bnb[i] - mean * a;
}

// ---------------- K3: per-row head scan: sparsemax (Michelot, max-seeded) -------
// 256 threads = 4 waves, each wave owns one row n. The sparsemax threshold
// satisfies max(z)-1 <= tau* < max(z), so seeding Michelot at tau0 = max-1
// starts from the few elements within 1.0 of the max (worst-case-bounded).
__global__ __launch_bounds__(256) void rows_kernel(const float* __restrict__ x,
                                                   const _Float16* __restrict__ lg,
                                                   const float* __restrict__ cA,
                                                   const float* __restrict__ cB,
                                                   float* __restrict__ out) {
    const int n    = blockIdx.x * 4 + (threadIdx.x >> 6);
    const int lane = threadIdx.x & 63;
    const int e0   = lane * 4;                 // first chunk; second at +256
    const int bb   = n >> 9;                   // n / Tt
    const int tt   = n & 511;                  // n % Tt

    float xr[8], prior[8];
    {
        const float* xp = x + (size_t)n * Ee;
        float4 x0 = *(const float4*)(xp + e0);
        float4 x1 = *(const float4*)(xp + 256 + e0);
        xr[0]=x0.x; xr[1]=x0.y; xr[2]=x0.z; xr[3]=x0.w;
        xr[4]=x1.x; xr[5]=x1.y; xr[6]=x1.z; xr[7]=x1.w;
    }
#pragma unroll
    for (int j = 0; j < 8; ++j) prior[j] = 1.0f;

    float* omx = out;                               // (H,B,T,E) flat = (H,N,E)
    float* omk = out + (size_t)Hh * Nn * Ee;        // (B,H,T,E)

    const _Float16* lrow = lg + (size_t)n * Ee;
    f16x4 l0 = *(const f16x4*)(lrow + e0);
    f16x4 l1 = *(const f16x4*)(lrow + 256 + e0);

#pragma unroll 1
    for (int h = 0; h < Hh; ++h) {
        // depth-1 prefetch of next head's logits (independent of prior chain)
        f16x4 p0 = l0, p1 = l1;
        if (h + 1 < Hh) {
            const _Float16* lnx = lrow + (size_t)(h + 1) * Nn * Ee;
            p0 = *(const f16x4*)(lnx + e0);
            p1 = *(const f16x4*)(lnx + 256 + e0);
        }
        float z[8];
        {
            const float* ap = cA + h * Ee + e0;
            const float* bp = cB + h * Ee + e0;
            float4 a0 = *(const float4*)(ap);
            float4 b0 = *(const float4*)(bp);
            float4 a1 = *(const float4*)(ap + 256);
            float4 b1 = *(const float4*)(bp + 256);
            z[0] = ((float)l0[0] * a0.x + b0.x) * prior[0];
            z[1] = ((float)l0[1] * a0.y + b0.y) * prior[1];
            z[2] = ((float)l0[2] * a0.z + b0.z) * prior[2];
            z[3] = ((float)l0[3] * a0.w + b0.w) * prior[3];
            z[4] = ((float)l1[0] * a1.x + b1.x) * prior[4];
            z[5] = ((float)l1[1] * a1.y + b1.y) * prior[5];
            z[6] = ((float)l1[2] * a1.z + b1.z) * prior[6];
            z[7] = ((float)l1[3] * a1.w + b1.w) * prior[7];
        }

        // Michelot seeded at tau0 = max - 1 (exact sparsemax threshold).
        float mx = z[0];
#pragma unroll
        for (int j = 1; j < 8; ++j) mx = fmaxf(mx, z[j]);
        float tau = dpp_max64(mx) - 1.0f;
        int cprev = -1;
#pragma unroll 1
        for (int it = 0; it < 64; ++it) {
            float s2 = 0.f;
            int cnt = 0;
#pragma unroll
            for (int j = 0; j < 8; ++j) {
                bool p = z[j] > tau;
                s2 += p ? z[j] : 0.0f;
                cnt += (int)__popcll(__ballot(p));
            }
            float S = dpp_sum64(s2);
            if (cnt == cprev) break;
            cprev = cnt;
            tau = (S - 1.0f) / (float)cnt;
        }

        size_t oxoff = ((size_t)h * Nn + n) * Ee + e0;
        size_t okoff = (((size_t)bb * Hh + h) * Tt + tt) * Ee + e0;
        f32x4 vx, vm;
#pragma unroll
        for (int j = 0; j < 4; ++j) {
            float m = fmaxf(z[j] - tau, 0.0f);
            prior[j] *= fmaxf(GAMMA_ - m, 0.0f);
            vm[j] = m; vx[j] = xr[j] * m;
        }
        __builtin_nontemporal_store(vx, (f32x4*)(omx + oxoff));
        __builtin_nontemporal_store(vm, (f32x4*)(omk + okoff));
#pragma unroll
        for (int j = 0; j < 4; ++j) {
            float m = fmaxf(z[4 + j] - tau, 0.0f);
            prior[4 + j] *= fmaxf(GAMMA_ - m, 0.0f);
            vm[j] = m; vx[j] = xr[4 + j] * m;
        }
        __builtin_nontemporal_store(vx, (f32x4*)(omx + oxoff + 256));
        __builtin_nontemporal_store(vm, (f32x4*)(omk + okoff + 256));
        l0 = p0; l1 = p1;
    }
}

extern "C" void kernel_launch(void* const* d_in, const int* in_sizes, int n_in,
                              void* d_out, int out_size, void* d_ws, size_t ws_size,
                              hipStream_t stream) {
    const float* x   = (const float*)d_in[0];
    const float* W   = (const float*)d_in[1];
    const float* bnw = (const float*)d_in[2];
    const float* bnb = (const float*)d_in[3];
    float* out = (float*)d_out;

    uint8_t* ws = (uint8_t*)d_ws;
    _Float16* xh = (_Float16*)(ws);                    // 16,777,216 B
    _Float16* wh = (_Float16*)(ws + 16777216);         //  4,194,304 B
    _Float16* lg = (_Float16*)(ws + 20971520);         // 134,217,728 B
    float* sums  = (float*)(ws + 155189248);           // 16,384 B
    float* sumsq = (float*)(ws + 155205632);           // 16,384 B
    float* cA    = (float*)(ws + 155222016);           // 16,384 B
    float* cB    = (float*)(ws + 155238400);           // 16,384 B (total ~148 MB)

    hipMemsetAsync(sums, 0, 2 * 4096 * sizeof(float), stream);  // sums+sumsq contiguous

    cvt_kernel<<<10240, 256, 0, stream>>>(x, W, xh, wh);
    gemm_kernel<<<1024, 512, 0, stream>>>(xh, wh, lg, sums, sumsq);
    stats_kernel<<<16, 256, 0, stream>>>(sums, sumsq, bnw, bnb, cA, cB);
    rows_kernel<<<4096, 256, 0, stream>>>(x, lg, cA, cB, out);
}

// Round 4
// 653.659 us; speedup vs baseline: 1.0197x; 1.0197x over previous
//
#include <hip/hip_runtime.h>
#include <stdint.h>

#define Hh 8
#define Bb 32
#define Tt 512
#define Ee 512
#define Nn 16384            // Bb*Tt
#define GAMMA_ 1.5f
#define BN_EPS_ 1e-5f

typedef _Float16 f16x4 __attribute__((ext_vector_type(4)));
typedef _Float16 f16x8 __attribute__((ext_vector_type(8)));
typedef float    f32x4 __attribute__((ext_vector_type(4)));

__device__ __forceinline__ void async_ld16(void* lds, const void* g) {
    __builtin_amdgcn_global_load_lds(
        (const __attribute__((address_space(1))) void*)g,
        (__attribute__((address_space(3))) void*)lds, 16, 0, 0);
}

// Full-wave (64-lane) f32 sum via DPP (pure VALU, no DS pipe).
__device__ __forceinline__ float dpp_sum64(float v) {
    int t;
    t = __builtin_amdgcn_update_dpp(0, __float_as_int(v), 0x111, 0xf, 0xf, true);
    v += __int_as_float(t);
    t = __builtin_amdgcn_update_dpp(0, __float_as_int(v), 0x112, 0xf, 0xf, true);
    v += __int_as_float(t);
    t = __builtin_amdgcn_update_dpp(0, __float_as_int(v), 0x114, 0xf, 0xf, true);
    v += __int_as_float(t);
    t = __builtin_amdgcn_update_dpp(0, __float_as_int(v), 0x118, 0xf, 0xf, true);
    v += __int_as_float(t);
    t = __builtin_amdgcn_update_dpp(0, __float_as_int(v), 0x142, 0xf, 0xf, true);
    v += __int_as_float(t);
    t = __builtin_amdgcn_update_dpp(0, __float_as_int(v), 0x143, 0xf, 0xf, true);
    v += __int_as_float(t);
    return __int_as_float(__builtin_amdgcn_readlane(__float_as_int(v), 63));
}

// Full-wave f32 max via DPP. old=src + bound_ctrl=false => invalid lanes are
// identity under fmax (no 0.0 injection; safe for all-negative inputs).
__device__ __forceinline__ float dpp_max64(float v) {
    int t;
    t = __builtin_amdgcn_update_dpp(__float_as_int(v), __float_as_int(v), 0x111, 0xf, 0xf, false);
    v = fmaxf(v, __int_as_float(t));
    t = __builtin_amdgcn_update_dpp(__float_as_int(v), __float_as_int(v), 0x112, 0xf, 0xf, false);
    v = fmaxf(v, __int_as_float(t));
    t = __builtin_amdgcn_update_dpp(__float_as_int(v), __float_as_int(v), 0x114, 0xf, 0xf, false);
    v = fmaxf(v, __int_as_float(t));
    t = __builtin_amdgcn_update_dpp(__float_as_int(v), __float_as_int(v), 0x118, 0xf, 0xf, false);
    v = fmaxf(v, __int_as_float(t));
    t = __builtin_amdgcn_update_dpp(__float_as_int(v), __float_as_int(v), 0x142, 0xf, 0xf, false);
    v = fmaxf(v, __int_as_float(t));
    t = __builtin_amdgcn_update_dpp(__float_as_int(v), __float_as_int(v), 0x143, 0xf, 0xf, false);
    v = fmaxf(v, __int_as_float(t));
    return __int_as_float(__builtin_amdgcn_readlane(__float_as_int(v), 63));
}

// ---------------- K0: fp32 -> f16 convert (x then W, contiguous) ----------------
__global__ __launch_bounds__(256) void cvt_kernel(const float* __restrict__ x,
                                                  const float* __restrict__ W,
                                                  _Float16* __restrict__ xh,
                                                  _Float16* __restrict__ wh) {
    const int NX = Bb * Tt * Ee;               // 8388608, divisible by 4
    int i = (blockIdx.x * 256 + threadIdx.x) * 4;
    if (i < NX) {
        float4 v = *(const float4*)(x + i);
        f16x4 o = {(_Float16)v.x, (_Float16)v.y, (_Float16)v.z, (_Float16)v.w};
        *(f16x4*)(xh + i) = o;
    } else {
        int j = i - NX;                        // 0 .. 2097151
        float4 v = *(const float4*)(W + j);
        f16x4 o = {(_Float16)v.x, (_Float16)v.y, (_Float16)v.z, (_Float16)v.w};
        *(f16x4*)(wh + j) = o;
    }
}

// ---------------- K1: batched NT GEMM, 256x256 tiles, BK=64, f16 MFMA -----------
// vs round-2 (2-phase BK=32): (a) BK=64 dbuf halves barrier count and doubles
// prefetch lead (~600cy, covers L2 latency); (b) B-fragments hoisted per tile
// (8 ds_read_b128 once, reused by all 8 mt); (c) setprio(1) around MFMA
// clusters -- waves free-run between tile barriers, so the CU scheduler has
// role diversity to arbitrate (T5 mechanism); (d) XCD swizzle: blocks of one
// head land on one XCD -> 512KB B-panel is L2-resident (T1).
// LDS 128 KB (1 block/CU -- unchanged: VGPR already caps at 2 waves/SIMD).
// Rotate swizzle (8 chunks of 16B per 128B row): chunk c of row r lives at
// slot (c + (r>>1)) & 7 -> ds_read_b128 lands 2 lanes/bank (free).
__global__ __launch_bounds__(512, 2) void gemm_kernel(const _Float16* __restrict__ A,
                                                      const _Float16* __restrict__ Bm,
                                                      _Float16* __restrict__ C,
                                                      float* __restrict__ sums,
                                                      float* __restrict__ sumsq) {
    __shared__ alignas(16) _Float16 As[2][256 * 64];   // 2 x 32 KB
    __shared__ alignas(16) _Float16 Bs[2][256 * 64];   // 2 x 32 KB
    // XCD-aware swizzle: 1024 blocks, 8 XCDs, 128 blocks (one head) per XCD.
    const int id  = (blockIdx.x & 7) * 128 + (blockIdx.x >> 3);
    const int h   = id >> 7;
    const int rem = id & 127;
    const int mb  = (rem >> 1) * 256;          // 64 row-blocks
    const int nb  = (rem & 1) * 256;           // 2 col-blocks

    const int t    = threadIdx.x;              // 0..511
    const int lane = t & 63;
    const int w    = t >> 6;                   // 0..7
    const int wrow = (w >> 2) * 128;           // 0,128
    const int wcol = (w & 3) * 64;             // 0,64,128,192
    const int quad = lane >> 4;
    const int l16  = lane & 15;

    // staging: thread t writes 4 chunks of A (rows t>>3 +{0,64,128,192}, slot
    // t&7) and same for B. Global k-chunk c = (slot - (row>>1)) & 7; identical
    // for all 4 rows since +64 ≡ 0 mod 8 after >>1.
    const int c = ((t & 7) - ((t >> 4) & 7)) & 7;
    const _Float16* Ap = A + (size_t)(mb + (t >> 3)) * Ee + c * 8;
    const _Float16* Bp = Bm + (size_t)h * Ee * Ee + (size_t)(nb + (t >> 3)) * Ee + c * 8;

    f32x4 acc[8][4] = {};

    // prologue: stage tile 0 into buf 0 (8 loads/thread)
#pragma unroll
    for (int q = 0; q < 4; ++q) {
        async_ld16(&As[0][q * 4096 + t * 8], Ap + q * 64 * Ee);
        async_ld16(&Bs[0][q * 4096 + t * 8], Bp + q * 64 * Ee);
    }

#pragma unroll 1
    for (int tile = 0; tile < 8; ++tile) {     // 8 K-tiles of 64
        const int cur = tile & 1;
        asm volatile("s_waitcnt vmcnt(0)" ::: "memory");
        __builtin_amdgcn_s_barrier();
        asm volatile("" ::: "memory");

        if (tile < 7) {                        // stage tile+1 into buf cur^1
            const _Float16* Aps = Ap + (tile + 1) * 64;
            const _Float16* Bps = Bp + (tile + 1) * 64;
#pragma unroll
            for (int q = 0; q < 4; ++q) {
                async_ld16(&As[cur ^ 1][q * 4096 + t * 8], Aps + q * 64 * Ee);
                async_ld16(&Bs[cur ^ 1][q * 4096 + t * 8], Bps + q * 64 * Ee);
            }
        }

        // B fragments for the whole tile: 8 x ds_read_b128, reused by all mt
        f16x8 b8[4][2];
#pragma unroll
        for (int nt = 0; nt < 4; ++nt)
#pragma unroll
            for (int kk = 0; kk < 2; ++kk) {
                int row  = wcol + nt * 16 + l16;
                int slot = ((kk * 4 + quad) + ((row >> 1) & 7)) & 7;
                b8[nt][kk] = *(const f16x8*)(&Bs[cur][row * 64 + slot * 8]);
            }
#pragma unroll
        for (int mt = 0; mt < 8; ++mt) {
            f16x8 a8[2];
#pragma unroll
            for (int kk = 0; kk < 2; ++kk) {
                int row  = wrow + mt * 16 + l16;
                int slot = ((kk * 4 + quad) + ((row >> 1) & 7)) & 7;
                a8[kk] = *(const f16x8*)(&As[cur][row * 64 + slot * 8]);
            }
            __builtin_amdgcn_s_setprio(1);
#pragma unroll
            for (int nt = 0; nt < 4; ++nt) {
                acc[mt][nt] = __builtin_amdgcn_mfma_f32_16x16x32_f16(a8[0], b8[nt][0], acc[mt][nt], 0, 0, 0);
                acc[mt][nt] = __builtin_amdgcn_mfma_f32_16x16x32_f16(a8[1], b8[nt][1], acc[mt][nt], 0, 0, 0);
            }
            __builtin_amdgcn_s_setprio(0);
        }
    }

    // BN partial sums: reduce over rows (mt,r) then across quads (lanes xor 16,32)
#pragma unroll
    for (int nt = 0; nt < 4; ++nt) {
        float sv = 0.f, ss = 0.f;
#pragma unroll
        for (int mt = 0; mt < 8; ++mt)
#pragma unroll
            for (int rr = 0; rr < 4; ++rr) { float v = acc[mt][nt][rr]; sv += v; ss += v * v; }
        sv += __shfl_xor(sv, 16, 64); sv += __shfl_xor(sv, 32, 64);
        ss += __shfl_xor(ss, 16, 64); ss += __shfl_xor(ss, 32, 64);
        if (quad == 0) {
            int col = nb + wcol + nt * 16 + l16;
            atomicAdd(&sums[h * Ee + col], sv);
            atomicAdd(&sumsq[h * Ee + col], ss);
        }
    }

    // store C (f16): C/D layout col=lane&15, row=quad*4+reg
    _Float16* Cp = C + (size_t)h * Nn * Ee;
#pragma unroll
    for (int mt = 0; mt < 8; ++mt)
#pragma unroll
        for (int rr = 0; rr < 4; ++rr) {
            int row = mb + wrow + mt * 16 + quad * 4 + rr;
            size_t off = (size_t)row * Ee + nb + wcol + l16;
#pragma unroll
            for (int nt = 0; nt < 4; ++nt)
                Cp[off + nt * 16] = (_Float16)acc[mt][nt][rr];
        }
}

// ---------------- K2: finalize BN stats into affine coefs -----------------------
__global__ __launch_bounds__(256) void stats_kernel(const float* __restrict__ sums,
                                                    const float* __restrict__ sumsq,
                                                    const float* __restrict__ bnw,
                                                    const float* __restrict__ bnb,
                                                    float* __restrict__ cA,
                                                    float* __restrict__ cB) {
    int i = blockIdx.x * 256 + threadIdx.x;    // 0..4095
    float mean = sums[i] * (1.0f / Nn);
    float var  = sumsq[i] * (1.0f / Nn) - mean * mean;
    float inv  = rsqrtf(var + BN_EPS_);
    float a    = bnw[i] * inv;
    cA[i] = a;
    cB[i] = bnb[i] - mean * a;
}

// ---------------- K3: per-row head scan: sparsemax (Michelot, max-seeded) -------
// 256 threads = 4 waves, each wave owns one row n. The sparsemax threshold
// satisfies max(z)-1 <= tau* < max(z), so seeding Michelot at tau0 = max-1
// starts from the few elements within 1.0 of the max (worst-case-bounded).
__global__ __launch_bounds__(256) void rows_kernel(const float* __restrict__ x,
                                                   const _Float16* __restrict__ lg,
                                                   const float* __restrict__ cA,
                                                   const float* __restrict__ cB,
                                                   float* __restrict__ out) {
    const int n    = blockIdx.x * 4 + (threadIdx.x >> 6);
    const int lane = threadIdx.x & 63;
    const int e0   = lane * 4;                 // first chunk; second at +256
    const int bb   = n >> 9;                   // n / Tt
    const int tt   = n & 511;                  // n % Tt

    float xr[8], prior[8];
    {
        const float* xp = x + (size_t)n * Ee;
        float4 x0 = *(const float4*)(xp + e0);
        float4 x1 = *(const float4*)(xp + 256 + e0);
        xr[0]=x0.x; xr[1]=x0.y; xr[2]=x0.z; xr[3]=x0.w;
        xr[4]=x1.x; xr[5]=x1.y; xr[6]=x1.z; xr[7]=x1.w;
    }
#pragma unroll
    for (int j = 0; j < 8; ++j) prior[j] = 1.0f;

    float* omx = out;                               // (H,B,T,E) flat = (H,N,E)
    float* omk = out + (size_t)Hh * Nn * Ee;        // (B,H,T,E)

    const _Float16* lrow = lg + (size_t)n * Ee;
    f16x4 l0 = *(const f16x4*)(lrow + e0);
    f16x4 l1 = *(const f16x4*)(lrow + 256 + e0);

#pragma unroll 1
    for (int h = 0; h < Hh; ++h) {
        // depth-1 prefetch of next head's logits (independent of prior chain)
        f16x4 p0 = l0, p1 = l1;
        if (h + 1 < Hh) {
            const _Float16* lnx = lrow + (size_t)(h + 1) * Nn * Ee;
            p0 = *(const f16x4*)(lnx + e0);
            p1 = *(const f16x4*)(lnx + 256 + e0);
        }
        float z[8];
        {
            const float* ap = cA + h * Ee + e0;
            const float* bp = cB + h * Ee + e0;
            float4 a0 = *(const float4*)(ap);
            float4 b0 = *(const float4*)(bp);
            float4 a1 = *(const float4*)(ap + 256);
            float4 b1 = *(const float4*)(bp + 256);
            z[0] = ((float)l0[0] * a0.x + b0.x) * prior[0];
            z[1] = ((float)l0[1] * a0.y + b0.y) * prior[1];
            z[2] = ((float)l0[2] * a0.z + b0.z) * prior[2];
            z[3] = ((float)l0[3] * a0.w + b0.w) * prior[3];
            z[4] = ((float)l1[0] * a1.x + b1.x) * prior[4];
            z[5] = ((float)l1[1] * a1.y + b1.y) * prior[5];
            z[6] = ((float)l1[2] * a1.z + b1.z) * prior[6];
            z[7] = ((float)l1[3] * a1.w + b1.w) * prior[7];
        }

        // Michelot seeded at tau0 = max - 1 (exact sparsemax threshold).
        float mx = z[0];
#pragma unroll
        for (int j = 1; j < 8; ++j) mx = fmaxf(mx, z[j]);
        float tau = dpp_max64(mx) - 1.0f;
        int cprev = -1;
#pragma unroll 1
        for (int it = 0; it < 64; ++it) {
            float s2 = 0.f;
            int cnt = 0;
#pragma unroll
            for (int j = 0; j < 8; ++j) {
                bool p = z[j] > tau;
                s2 += p ? z[j] : 0.0f;
                cnt += (int)__popcll(__ballot(p));
            }
            float S = dpp_sum64(s2);
            if (cnt == cprev) break;
            cprev = cnt;
            tau = (S - 1.0f) / (float)cnt;
        }

        size_t oxoff = ((size_t)h * Nn + n) * Ee + e0;
        size_t okoff = (((size_t)bb * Hh + h) * Tt + tt) * Ee + e0;
        f32x4 vx, vm;
#pragma unroll
        for (int j = 0; j < 4; ++j) {
            float m = fmaxf(z[j] - tau, 0.0f);
            prior[j] *= fmaxf(GAMMA_ - m, 0.0f);
            vm[j] = m; vx[j] = xr[j] * m;
        }
        __builtin_nontemporal_store(vx, (f32x4*)(omx + oxoff));
        __builtin_nontemporal_store(vm, (f32x4*)(omk + okoff));
#pragma unroll
        for (int j = 0; j < 4; ++j) {
            float m = fmaxf(z[4 + j] - tau, 0.0f);
            prior[4 + j] *= fmaxf(GAMMA_ - m, 0.0f);
            vm[j] = m; vx[j] = xr[4 + j] * m;
        }
        __builtin_nontemporal_store(vx, (f32x4*)(omx + oxoff + 256));
        __builtin_nontemporal_store(vm, (f32x4*)(omk + okoff + 256));
        l0 = p0; l1 = p1;
    }
}

extern "C" void kernel_launch(void* const* d_in, const int* in_sizes, int n_in,
                              void* d_out, int out_size, void* d_ws, size_t ws_size,
                              hipStream_t stream) {
    const float* x   = (const float*)d_in[0];
    const float* W   = (const float*)d_in[1];
    const float* bnw = (const float*)d_in[2];
    const float* bnb = (const float*)d_in[3];
    float* out = (float*)d_out;

    uint8_t* ws = (uint8_t*)d_ws;
    _Float16* xh = (_Float16*)(ws);                    // 16,777,216 B
    _Float16* wh = (_Float16*)(ws + 16777216);         //  4,194,304 B
    _Float16* lg = (_Float16*)(ws + 20971520);         // 134,217,728 B
    float* sums  = (float*)(ws + 155189248);           // 16,384 B
    float* sumsq = (float*)(ws + 155205632);           // 16,384 B
    float* cA    = (float*)(ws + 155222016);           // 16,384 B
    float* cB    = (float*)(ws + 155238400);           // 16,384 B (total ~148 MB)

    hipMemsetAsync(sums, 0, 2 * 4096 * sizeof(float), stream);  // sums+sumsq contiguous

    cvt_kernel<<<10240, 256, 0, stream>>>(x, W, xh, wh);
    gemm_kernel<<<1024, 512, 0, stream>>>(xh, wh, lg, sums, sumsq);
    stats_kernel<<<16, 256, 0, stream>>>(sums, sumsq, bnw, bnb, cA, cB);
    rows_kernel<<<4096, 256, 0, stream>>>(x, lg, cA, cB, out);
}

// Round 5
// 649.612 us; speedup vs baseline: 1.0260x; 1.0062x over previous
//
#include <hip/hip_runtime.h>
#include <stdint.h>

#define Hh 8
#define Bb 32
#define Tt 512
#define Ee 512
#define Nn 16384            // Bb*Tt
#define GAMMA_ 1.5f
#define BN_EPS_ 1e-5f

typedef _Float16 f16x4 __attribute__((ext_vector_type(4)));
typedef _Float16 f16x8 __attribute__((ext_vector_type(8)));
typedef float    f32x4 __attribute__((ext_vector_type(4)));

__device__ __forceinline__ void async_ld16(void* lds, const void* g) {
    __builtin_amdgcn_global_load_lds(
        (const __attribute__((address_space(1))) void*)g,
        (__attribute__((address_space(3))) void*)lds, 16, 0, 0);
}

// Full-wave (64-lane) f32 sum via DPP (pure VALU, no DS pipe).
__device__ __forceinline__ float dpp_sum64(float v) {
    int t;
    t = __builtin_amdgcn_update_dpp(0, __float_as_int(v), 0x111, 0xf, 0xf, true);
    v += __int_as_float(t);
    t = __builtin_amdgcn_update_dpp(0, __float_as_int(v), 0x112, 0xf, 0xf, true);
    v += __int_as_float(t);
    t = __builtin_amdgcn_update_dpp(0, __float_as_int(v), 0x114, 0xf, 0xf, true);
    v += __int_as_float(t);
    t = __builtin_amdgcn_update_dpp(0, __float_as_int(v), 0x118, 0xf, 0xf, true);
    v += __int_as_float(t);
    t = __builtin_amdgcn_update_dpp(0, __float_as_int(v), 0x142, 0xf, 0xf, true);
    v += __int_as_float(t);
    t = __builtin_amdgcn_update_dpp(0, __float_as_int(v), 0x143, 0xf, 0xf, true);
    v += __int_as_float(t);
    return __int_as_float(__builtin_amdgcn_readlane(__float_as_int(v), 63));
}

// Full-wave f32 max via DPP. old=src + bound_ctrl=false => invalid lanes are
// identity under fmax (no 0.0 injection; safe for all-negative inputs).
__device__ __forceinline__ float dpp_max64(float v) {
    int t;
    t = __builtin_amdgcn_update_dpp(__float_as_int(v), __float_as_int(v), 0x111, 0xf, 0xf, false);
    v = fmaxf(v, __int_as_float(t));
    t = __builtin_amdgcn_update_dpp(__float_as_int(v), __float_as_int(v), 0x112, 0xf, 0xf, false);
    v = fmaxf(v, __int_as_float(t));
    t = __builtin_amdgcn_update_dpp(__float_as_int(v), __float_as_int(v), 0x114, 0xf, 0xf, false);
    v = fmaxf(v, __int_as_float(t));
    t = __builtin_amdgcn_update_dpp(__float_as_int(v), __float_as_int(v), 0x118, 0xf, 0xf, false);
    v = fmaxf(v, __int_as_float(t));
    t = __builtin_amdgcn_update_dpp(__float_as_int(v), __float_as_int(v), 0x142, 0xf, 0xf, false);
    v = fmaxf(v, __int_as_float(t));
    t = __builtin_amdgcn_update_dpp(__float_as_int(v), __float_as_int(v), 0x143, 0xf, 0xf, false);
    v = fmaxf(v, __int_as_float(t));
    return __int_as_float(__builtin_amdgcn_readlane(__float_as_int(v), 63));
}

// ---------------- K0: fp32 -> f16 convert (x then W, contiguous) ----------------
__global__ __launch_bounds__(256) void cvt_kernel(const float* __restrict__ x,
                                                  const float* __restrict__ W,
                                                  _Float16* __restrict__ xh,
                                                  _Float16* __restrict__ wh) {
    const int NX = Bb * Tt * Ee;               // 8388608, divisible by 4
    int i = (blockIdx.x * 256 + threadIdx.x) * 4;
    if (i < NX) {
        float4 v = *(const float4*)(x + i);
        f16x4 o = {(_Float16)v.x, (_Float16)v.y, (_Float16)v.z, (_Float16)v.w};
        *(f16x4*)(xh + i) = o;
    } else {
        int j = i - NX;                        // 0 .. 2097151
        float4 v = *(const float4*)(W + j);
        f16x4 o = {(_Float16)v.x, (_Float16)v.y, (_Float16)v.z, (_Float16)v.w};
        *(f16x4*)(wh + j) = o;
    }
}

// ---------------- K1: batched NT GEMM, 256x256 tiles, f16 MFMA ------------------
// T3+T4 proper: BK=32, TRIPLE-buffered LDS (3x16KB per matrix, 96 KB total).
// Loads for tile t are issued during tile t-2 (~4 phases lead, covers HBM
// latency); the tile-start wait is a COUNTED vmcnt(4) -- tile t+1's 4 loads
// stay in flight across the barrier; vmcnt(0) only at the last tile (m218:
// counted-vs-drain0 is the +38-73% lever; impossible with 2 buffers since at
// each boundary the only outstanding loads are the needed ones).
// Per tile: 2 phases of {ds_read frags || issue 2 stage loads -> barrier ->
// setprio(1) 16xMFMA setprio(0) -> barrier} (m196: the fine interleave is
// required). B-frags read in P0, reused in P1.
// WAR safety: stage for t+2 targets buf[(t+2)%3] == buf[(t-1)%3]; tile t-1's
// ds_reads returned before its MFMAs (compiler lgkmcnt), hence before all
// waves passed the tile-t start barrier; stages are issued after it.
// Rotate swizzle (4 chunks of 16B per 64B row): chunk c of row r at slot
// (c+((r>>1)&3))&3 -> ds_read_b128 at 2 lanes/bank (free). Same math as R2.
__global__ __launch_bounds__(512, 2) void gemm_kernel(const _Float16* __restrict__ A,
                                                      const _Float16* __restrict__ Bm,
                                                      _Float16* __restrict__ C,
                                                      float* __restrict__ sums,
                                                      float* __restrict__ sumsq) {
    __shared__ alignas(16) _Float16 As[3][256 * 32];   // 3 x 16 KB
    __shared__ alignas(16) _Float16 Bs[3][256 * 32];   // 3 x 16 KB
    // XCD-aware swizzle: 1024 blocks, 8 XCDs, 128 blocks (one head) per XCD.
    const int id  = (blockIdx.x & 7) * 128 + (blockIdx.x >> 3);
    const int h   = id >> 7;
    const int rem = id & 127;
    const int mb  = (rem >> 1) * 256;          // 64 row-blocks
    const int nb  = (rem & 1) * 256;           // 2 col-blocks

    const int t    = threadIdx.x;              // 0..511
    const int lane = t & 63;
    const int w    = t >> 6;                   // 0..7
    const int wrow = (w >> 2) * 128;           // 0,128
    const int wcol = (w & 3) * 64;             // 0,64,128,192
    const int quad = lane >> 4;
    const int l16  = lane & 15;

    // staging: thread t fills LDS chunks t and t+512 (rows t>>2 and 128+(t>>2),
    // slot t&3). Global k-chunk kc = (slot - (row>>1)) & 3; identical for both
    // chunks since +128 rows ≡ 0 mod 4 after >>1.
    const int kc = ((t & 3) - ((t >> 3) & 3)) & 3;
    const _Float16* Ap = A + (size_t)(mb + (t >> 2)) * Ee + kc * 8;
    const _Float16* Bp = Bm + (size_t)h * Ee * Ee + (size_t)(nb + (t >> 2)) * Ee + kc * 8;

    f32x4 acc[8][4] = {};

    // prologue: stage tiles 0,1 into bufs 0,1 (8 loads/thread in flight).
    // Per-tile issue order (A, A', B, B') is what the vmcnt counting assumes.
#pragma unroll
    for (int s = 0; s < 2; ++s) {
        async_ld16(&As[s][t * 8],        Ap + s * 32);
        async_ld16(&As[s][4096 + t * 8], Ap + 128 * Ee + s * 32);
        async_ld16(&Bs[s][t * 8],        Bp + s * 32);
        async_ld16(&Bs[s][4096 + t * 8], Bp + 128 * Ee + s * 32);
    }

    // reader slot: chunk `quad` of row R lives at slot (quad+(R>>1))&3;
    // (R>>1)&3 == (l16>>1)&3 for all wrow/wcol/mt/nt used here.
    const int so = ((quad + (l16 >> 1)) & 3) * 8;

#pragma unroll 1
    for (int tile = 0; tile < 16; ++tile) {    // 16 K-tiles of 32
        const int cur = tile % 3;
        // counted tile-start wait: retire tile's own 4 loads (oldest), keep
        // tile+1's 4 in flight. Only the last tile drains to 0.
        if (tile < 15) asm volatile("s_waitcnt vmcnt(4)" ::: "memory");
        else           asm volatile("s_waitcnt vmcnt(0)" ::: "memory");
        __builtin_amdgcn_s_barrier();
        asm volatile("" ::: "memory");

        const bool doStage = (tile + 2) < 16;
        const int  nxt = (tile + 2) % 3;
        const _Float16* Aps = Ap + (tile + 2) * 32;
        const _Float16* Bps = Bp + (tile + 2) * 32;

        // ---- phase 0: B frags + A frags mt0-3, stage A(t+2), 16 MFMA ----
        f16x8 b8[4], a8[4];
#pragma unroll
        for (int nt = 0; nt < 4; ++nt)
            b8[nt] = *(const f16x8*)(&Bs[cur][(wcol + nt * 16 + l16) * 32 + so]);
#pragma unroll
        for (int mt = 0; mt < 4; ++mt)
            a8[mt] = *(const f16x8*)(&As[cur][(wrow + mt * 16 + l16) * 32 + so]);
        if (doStage) {
            async_ld16(&As[nxt][t * 8],        Aps);
            async_ld16(&As[nxt][4096 + t * 8], Aps + 128 * Ee);
        }
        __builtin_amdgcn_s_barrier();
        asm volatile("" ::: "memory");
        __builtin_amdgcn_s_setprio(1);
#pragma unroll
        for (int mt = 0; mt < 4; ++mt)
#pragma unroll
            for (int nt = 0; nt < 4; ++nt)
                acc[mt][nt] = __builtin_amdgcn_mfma_f32_16x16x32_f16(a8[mt], b8[nt], acc[mt][nt], 0, 0, 0);
        __builtin_amdgcn_s_setprio(0);
        __builtin_amdgcn_s_barrier();
        asm volatile("" ::: "memory");

        // ---- phase 1: A frags mt4-7 (B reused), stage B(t+2), 16 MFMA ----
#pragma unroll
        for (int mt = 0; mt < 4; ++mt)
            a8[mt] = *(const f16x8*)(&As[cur][(wrow + (mt + 4) * 16 + l16) * 32 + so]);
        if (doStage) {
            async_ld16(&Bs[nxt][t * 8],        Bps);
            async_ld16(&Bs[nxt][4096 + t * 8], Bps + 128 * Ee);
        }
        __builtin_amdgcn_s_barrier();
        asm volatile("" ::: "memory");
        __builtin_amdgcn_s_setprio(1);
#pragma unroll
        for (int mt = 0; mt < 4; ++mt)
#pragma unroll
            for (int nt = 0; nt < 4; ++nt)
                acc[mt + 4][nt] = __builtin_amdgcn_mfma_f32_16x16x32_f16(a8[mt], b8[nt], acc[mt + 4][nt], 0, 0, 0);
        __builtin_amdgcn_s_setprio(0);
        // no trailing barrier: next tile's {vmcnt; barrier} closes this phase
        // (this tile's ds_reads returned before our MFMAs -> before that barrier)
    }

    // BN partial sums: reduce over rows (mt,r) then across quads (lanes xor 16,32)
#pragma unroll
    for (int nt = 0; nt < 4; ++nt) {
        float sv = 0.f, ss = 0.f;
#pragma unroll
        for (int mt = 0; mt < 8; ++mt)
#pragma unroll
            for (int rr = 0; rr < 4; ++rr) { float v = acc[mt][nt][rr]; sv += v; ss += v * v; }
        sv += __shfl_xor(sv, 16, 64); sv += __shfl_xor(sv, 32, 64);
        ss += __shfl_xor(ss, 16, 64); ss += __shfl_xor(ss, 32, 64);
        if (quad == 0) {
            int col = nb + wcol + nt * 16 + l16;
            atomicAdd(&sums[h * Ee + col], sv);
            atomicAdd(&sumsq[h * Ee + col], ss);
        }
    }

    // store C (f16): C/D layout col=lane&15, row=quad*4+reg
    _Float16* Cp = C + (size_t)h * Nn * Ee;
#pragma unroll
    for (int mt = 0; mt < 8; ++mt)
#pragma unroll
        for (int rr = 0; rr < 4; ++rr) {
            int row = mb + wrow + mt * 16 + quad * 4 + rr;
            size_t off = (size_t)row * Ee + nb + wcol + l16;
#pragma unroll
            for (int nt = 0; nt < 4; ++nt)
                Cp[off + nt * 16] = (_Float16)acc[mt][nt][rr];
        }
}

// ---------------- K2: finalize BN stats into affine coefs -----------------------
__global__ __launch_bounds__(256) void stats_kernel(const float* __restrict__ sums,
                                                    const float* __restrict__ sumsq,
                                                    const float* __restrict__ bnw,
                                                    const float* __restrict__ bnb,
                                                    float* __restrict__ cA,
                                                    float* __restrict__ cB) {
    int i = blockIdx.x * 256 + threadIdx.x;    // 0..4095
    float mean = sums[i] * (1.0f / Nn);
    float var  = sumsq[i] * (1.0f / Nn) - mean * mean;
    float inv  = rsqrtf(var + BN_EPS_);
    float a    = bnw[i] * inv;
    cA[i] = a;
    cB[i] = bnb[i] - mean * a;
}

// ---------------- K3: per-row head scan: sparsemax (Michelot, max-seeded) -------
// 256 threads = 4 waves, each wave owns one row n. The sparsemax threshold
// satisfies max(z)-1 <= tau* < max(z), so seeding Michelot at tau0 = max-1
// starts from the few elements within 1.0 of the max (worst-case-bounded).
__global__ __launch_bounds__(256) void rows_kernel(const float* __restrict__ x,
                                                   const _Float16* __restrict__ lg,
                                                   const float* __restrict__ cA,
                                                   const float* __restrict__ cB,
                                                   float* __restrict__ out) {
    const int n    = blockIdx.x * 4 + (threadIdx.x >> 6);
    const int lane = threadIdx.x & 63;
    const int e0   = lane * 4;                 // first chunk; second at +256
    const int bb   = n >> 9;                   // n / Tt
    const int tt   = n & 511;                  // n % Tt

    float xr[8], prior[8];
    {
        const float* xp = x + (size_t)n * Ee;
        float4 x0 = *(const float4*)(xp + e0);
        float4 x1 = *(const float4*)(xp + 256 + e0);
        xr[0]=x0.x; xr[1]=x0.y; xr[2]=x0.z; xr[3]=x0.w;
        xr[4]=x1.x; xr[5]=x1.y; xr[6]=x1.z; xr[7]=x1.w;
    }
#pragma unroll
    for (int j = 0; j < 8; ++j) prior[j] = 1.0f;

    float* omx = out;                               // (H,B,T,E) flat = (H,N,E)
    float* omk = out + (size_t)Hh * Nn * Ee;        // (B,H,T,E)

    const _Float16* lrow = lg + (size_t)n * Ee;
    f16x4 l0 = *(const f16x4*)(lrow + e0);
    f16x4 l1 = *(const f16x4*)(lrow + 256 + e0);

#pragma unroll 1
    for (int h = 0; h < Hh; ++h) {
        // depth-1 prefetch of next head's logits (independent of prior chain)
        f16x4 p0 = l0, p1 = l1;
        if (h + 1 < Hh) {
            const _Float16* lnx = lrow + (size_t)(h + 1) * Nn * Ee;
            p0 = *(const f16x4*)(lnx + e0);
            p1 = *(const f16x4*)(lnx + 256 + e0);
        }
        float z[8];
        {
            const float* ap = cA + h * Ee + e0;
            const float* bp = cB + h * Ee + e0;
            float4 a0 = *(const float4*)(ap);
            float4 b0 = *(const float4*)(bp);
            float4 a1 = *(const float4*)(ap + 256);
            float4 b1 = *(const float4*)(bp + 256);
            z[0] = ((float)l0[0] * a0.x + b0.x) * prior[0];
            z[1] = ((float)l0[1] * a0.y + b0.y) * prior[1];
            z[2] = ((float)l0[2] * a0.z + b0.z) * prior[2];
            z[3] = ((float)l0[3] * a0.w + b0.w) * prior[3];
            z[4] = ((float)l1[0] * a1.x + b1.x) * prior[4];
            z[5] = ((float)l1[1] * a1.y + b1.y) * prior[5];
            z[6] = ((float)l1[2] * a1.z + b1.z) * prior[6];
            z[7] = ((float)l1[3] * a1.w + b1.w) * prior[7];
        }

        // Michelot seeded at tau0 = max - 1 (exact sparsemax threshold).
        float mx = z[0];
#pragma unroll
        for (int j = 1; j < 8; ++j) mx = fmaxf(mx, z[j]);
        float tau = dpp_max64(mx) - 1.0f;
        int cprev = -1;
#pragma unroll 1
        for (int it = 0; it < 64; ++it) {
            float s2 = 0.f;
            int cnt = 0;
#pragma unroll
            for (int j = 0; j < 8; ++j) {
                bool p = z[j] > tau;
                s2 += p ? z[j] : 0.0f;
                cnt += (int)__popcll(__ballot(p));
            }
            float S = dpp_sum64(s2);
            if (cnt == cprev) break;
            cprev = cnt;
            tau = (S - 1.0f) / (float)cnt;
        }

        size_t oxoff = ((size_t)h * Nn + n) * Ee + e0;
        size_t okoff = (((size_t)bb * Hh + h) * Tt + tt) * Ee + e0;
        f32x4 vx, vm;
#pragma unroll
        for (int j = 0; j < 4; ++j) {
            float m = fmaxf(z[j] - tau, 0.0f);
            prior[j] *= fmaxf(GAMMA_ - m, 0.0f);
            vm[j] = m; vx[j] = xr[j] * m;
        }
        __builtin_nontemporal_store(vx, (f32x4*)(omx + oxoff));
        __builtin_nontemporal_store(vm, (f32x4*)(omk + okoff));
#pragma unroll
        for (int j = 0; j < 4; ++j) {
            float m = fmaxf(z[4 + j] - tau, 0.0f);
            prior[4 + j] *= fmaxf(GAMMA_ - m, 0.0f);
            vm[j] = m; vx[j] = xr[4 + j] * m;
        }
        __builtin_nontemporal_store(vx, (f32x4*)(omx + oxoff + 256));
        __builtin_nontemporal_store(vm, (f32x4*)(omk + okoff + 256));
        l0 = p0; l1 = p1;
    }
}

extern "C" void kernel_launch(void* const* d_in, const int* in_sizes, int n_in,
                              void* d_out, int out_size, void* d_ws, size_t ws_size,
                              hipStream_t stream) {
    const float* x   = (const float*)d_in[0];
    const float* W   = (const float*)d_in[1];
    const float* bnw = (const float*)d_in[2];
    const float* bnb = (const float*)d_in[3];
    float* out = (float*)d_out;

    uint8_t* ws = (uint8_t*)d_ws;
    _Float16* xh = (_Float16*)(ws);                    // 16,777,216 B
    _Float16* wh = (_Float16*)(ws + 16777216);         //  4,194,304 B
    _Float16* lg = (_Float16*)(ws + 20971520);         // 134,217,728 B
    float* sums  = (float*)(ws + 155189248);           // 16,384 B
    float* sumsq = (float*)(ws + 155205632);           // 16,384 B
    float* cA    = (float*)(ws + 155222016);           // 16,384 B
    float* cB    = (float*)(ws + 155238400);           // 16,384 B (total ~148 MB)

    hipMemsetAsync(sums, 0, 2 * 4096 * sizeof(float), stream);  // sums+sumsq contiguous

    cvt_kernel<<<10240, 256, 0, stream>>>(x, W, xh, wh);
    gemm_kernel<<<1024, 512, 0, stream>>>(xh, wh, lg, sums, sumsq);
    stats_kernel<<<16, 256, 0, stream>>>(sums, sumsq, bnw, bnb, cA, cB);
    rows_kernel<<<4096, 256, 0, stream>>>(x, lg, cA, cB, out);
}

// Round 6
// 646.332 us; speedup vs baseline: 1.0313x; 1.0051x over previous
//
#include <hip/hip_runtime.h>
#include <stdint.h>

#define Hh 8
#define Bb 32
#define Tt 512
#define Ee 512
#define Nn 16384            // Bb*Tt
#define GAMMA_ 1.5f
#define BN_EPS_ 1e-5f

typedef _Float16 f16x4 __attribute__((ext_vector_type(4)));
typedef _Float16 f16x8 __attribute__((ext_vector_type(8)));
typedef float    f32x4 __attribute__((ext_vector_type(4)));

__device__ __forceinline__ void async_ld16(void* lds, const void* g) {
    __builtin_amdgcn_global_load_lds(
        (const __attribute__((address_space(1))) void*)g,
        (__attribute__((address_space(3))) void*)lds, 16, 0, 0);
}

// Full-wave (64-lane) f32 sum via DPP (pure VALU, no DS pipe).
__device__ __forceinline__ float dpp_sum64(float v) {
    int t;
    t = __builtin_amdgcn_update_dpp(0, __float_as_int(v), 0x111, 0xf, 0xf, true);
    v += __int_as_float(t);
    t = __builtin_amdgcn_update_dpp(0, __float_as_int(v), 0x112, 0xf, 0xf, true);
    v += __int_as_float(t);
    t = __builtin_amdgcn_update_dpp(0, __float_as_int(v), 0x114, 0xf, 0xf, true);
    v += __int_as_float(t);
    t = __builtin_amdgcn_update_dpp(0, __float_as_int(v), 0x118, 0xf, 0xf, true);
    v += __int_as_float(t);
    t = __builtin_amdgcn_update_dpp(0, __float_as_int(v), 0x142, 0xf, 0xf, true);
    v += __int_as_float(t);
    t = __builtin_amdgcn_update_dpp(0, __float_as_int(v), 0x143, 0xf, 0xf, true);
    v += __int_as_float(t);
    return __int_as_float(__builtin_amdgcn_readlane(__float_as_int(v), 63));
}

// Full-wave f32 max via DPP. old=src + bound_ctrl=false => invalid lanes are
// identity under fmax (no 0.0 injection; safe for all-negative inputs).
__device__ __forceinline__ float dpp_max64(float v) {
    int t;
    t = __builtin_amdgcn_update_dpp(__float_as_int(v), __float_as_int(v), 0x111, 0xf, 0xf, false);
    v = fmaxf(v, __int_as_float(t));
    t = __builtin_amdgcn_update_dpp(__float_as_int(v), __float_as_int(v), 0x112, 0xf, 0xf, false);
    v = fmaxf(v, __int_as_float(t));
    t = __builtin_amdgcn_update_dpp(__float_as_int(v), __float_as_int(v), 0x114, 0xf, 0xf, false);
    v = fmaxf(v, __int_as_float(t));
    t = __builtin_amdgcn_update_dpp(__float_as_int(v), __float_as_int(v), 0x118, 0xf, 0xf, false);
    v = fmaxf(v, __int_as_float(t));
    t = __builtin_amdgcn_update_dpp(__float_as_int(v), __float_as_int(v), 0x142, 0xf, 0xf, false);
    v = fmaxf(v, __int_as_float(t));
    t = __builtin_amdgcn_update_dpp(__float_as_int(v), __float_as_int(v), 0x143, 0xf, 0xf, false);
    v = fmaxf(v, __int_as_float(t));
    return __int_as_float(__builtin_amdgcn_readlane(__float_as_int(v), 63));
}

// ---------------- K0: fp32 -> f16 convert (x then W) + zero BN accumulators -----
// The last 8 blocks also zero sums/sumsq (8192 floats = 2048 float4), replacing
// the separate hipMemsetAsync dispatch. Stream order guarantees zeros land
// before gemm's atomics.
__global__ __launch_bounds__(256) void cvt_kernel(const float* __restrict__ x,
                                                  const float* __restrict__ W,
                                                  _Float16* __restrict__ xh,
                                                  _Float16* __restrict__ wh,
                                                  float* __restrict__ sums) {
    const int NX = Bb * Tt * Ee;               // 8388608, divisible by 4
    const int tid_g = blockIdx.x * 256 + threadIdx.x;   // 0..2621439
    int i = tid_g * 4;
    if (i < NX) {
        float4 v = *(const float4*)(x + i);
        f16x4 o = {(_Float16)v.x, (_Float16)v.y, (_Float16)v.z, (_Float16)v.w};
        *(f16x4*)(xh + i) = o;
    } else {
        int j = i - NX;                        // 0 .. 2097151
        float4 v = *(const float4*)(W + j);
        f16x4 o = {(_Float16)v.x, (_Float16)v.y, (_Float16)v.z, (_Float16)v.w};
        *(f16x4*)(wh + j) = o;
    }
    int zi = tid_g - (2621440 - 2048);         // last 2048 threads
    if (zi >= 0) {
        float4 zz = {0.f, 0.f, 0.f, 0.f};
        ((float4*)sums)[zi] = zz;              // sums+sumsq contiguous, 32 KB
    }
}

// ---------------- K1: batched NT GEMM, 256x256 tiles, f16 MFMA, dbuf LDS --------
// R2-proven schedule (best measured). 512 threads = 8 waves (2 row x 4 col),
// each wave 128x64. 64 KB LDS -> 2 blocks/CU; inter-block overlap (m114) hides
// the per-tile vmcnt(0) drain, which is cheap anyway: staging is L2-resident
// (unique inputs 20 MB; A re-staged 16x, B 64x), so loads return in ~200 cy.
// Deeper pipelines (R3 coarse 4-buf, R4 BK=64, R5 counted-vmcnt 3-buf) all
// measured null-or-worse -- the counted-vmcnt lever pays at HBM latency, not
// here. K-chunk rotate swizzle keeps ds_read_b128 at the 2-lanes/bank minimum.
__global__ __launch_bounds__(512, 2) void gemm_kernel(const _Float16* __restrict__ A,
                                                      const _Float16* __restrict__ Bm,
                                                      _Float16* __restrict__ C,
                                                      float* __restrict__ sums,
                                                      float* __restrict__ sumsq) {
    __shared__ alignas(16) _Float16 As[2][256 * 32];   // 2 x 16 KB
    __shared__ alignas(16) _Float16 Bs[2][256 * 32];   // 2 x 16 KB
    const int id  = blockIdx.x;                // 0..1023
    const int h   = id >> 7;
    const int rem = id & 127;
    const int mb  = (rem >> 1) * 256;          // 64 row-blocks
    const int nb  = (rem & 1) * 256;           // 2 col-blocks

    const int t    = threadIdx.x;              // 0..511
    const int lane = t & 63;
    const int w    = t >> 6;                   // 0..7
    const int wrow = (w >> 2) * 128;           // 0,128
    const int wcol = (w & 3) * 64;             // 0,64,128,192
    const int quad = lane >> 4;
    const int l16  = lane & 15;

    // staging: thread t fills LDS chunks t and t+512 (rows t>>2 and 128+(t>>2),
    // slot t&3). Global k-chunk kc = (slot - (row>>1)) & 3; identical for both
    // chunks since +128 rows ≡ 0 mod 4 after >>1.
    const int kc = ((t & 3) - ((t >> 3) & 3)) & 3;
    const _Float16* Ap = A + (size_t)(mb + (t >> 2)) * Ee + kc * 8;
    const _Float16* Bp = Bm + (size_t)h * Ee * Ee + (size_t)(nb + (t >> 2)) * Ee + kc * 8;

    f32x4 acc[8][4] = {};

    // prologue: stage k0=0 into buf 0
    async_ld16(&As[0][t * 8],        Ap);
    async_ld16(&As[0][4096 + t * 8], Ap + 128 * Ee);
    async_ld16(&Bs[0][t * 8],        Bp);
    async_ld16(&Bs[0][4096 + t * 8], Bp + 128 * Ee);

    // reader slot: chunk `quad` of row R lives at slot (quad+(R>>1))&3;
    // (R>>1)&3 == (l16>>1)&3 for all wrow/wcol/mt/nt used here.
    const int so = ((quad + (l16 >> 1)) & 3) * 8;

    int buf = 0;
    for (int k0 = 0; k0 < Ee; k0 += 32) {
        __syncthreads();   // drains loads for `buf`; also closes reads of buf^1
        if (k0 + 32 < Ee) {
            int nx = buf ^ 1;
            async_ld16(&As[nx][t * 8],        Ap + k0 + 32);
            async_ld16(&As[nx][4096 + t * 8], Ap + 128 * Ee + k0 + 32);
            async_ld16(&Bs[nx][t * 8],        Bp + k0 + 32);
            async_ld16(&Bs[nx][4096 + t * 8], Bp + 128 * Ee + k0 + 32);
        }
        f16x8 b8[4];
#pragma unroll
        for (int nt = 0; nt < 4; ++nt)
            b8[nt] = *(const f16x8*)(&Bs[buf][(wcol + nt * 16 + l16) * 32 + so]);
#pragma unroll
        for (int mt = 0; mt < 8; ++mt) {
            f16x8 a8 = *(const f16x8*)(&As[buf][(wrow + mt * 16 + l16) * 32 + so]);
#pragma unroll
            for (int nt = 0; nt < 4; ++nt)
                acc[mt][nt] = __builtin_amdgcn_mfma_f32_16x16x32_f16(a8, b8[nt], acc[mt][nt], 0, 0, 0);
        }
        buf ^= 1;
    }

    // BN partial sums: reduce over rows (mt,r) then across quads (lanes xor 16,32)
#pragma unroll
    for (int nt = 0; nt < 4; ++nt) {
        float sv = 0.f, ss = 0.f;
#pragma unroll
        for (int mt = 0; mt < 8; ++mt)
#pragma unroll
            for (int rr = 0; rr < 4; ++rr) { float v = acc[mt][nt][rr]; sv += v; ss += v * v; }
        sv += __shfl_xor(sv, 16, 64); sv += __shfl_xor(sv, 32, 64);
        ss += __shfl_xor(ss, 16, 64); ss += __shfl_xor(ss, 32, 64);
        if (quad == 0) {
            int col = nb + wcol + nt * 16 + l16;
            atomicAdd(&sums[h * Ee + col], sv);
            atomicAdd(&sumsq[h * Ee + col], ss);
        }
    }

    // store C (f16): C/D layout col=lane&15, row=quad*4+reg
    _Float16* Cp = C + (size_t)h * Nn * Ee;
#pragma unroll
    for (int mt = 0; mt < 8; ++mt)
#pragma unroll
        for (int rr = 0; rr < 4; ++rr) {
            int row = mb + wrow + mt * 16 + quad * 4 + rr;
            size_t off = (size_t)row * Ee + nb + wcol + l16;
#pragma unroll
            for (int nt = 0; nt < 4; ++nt)
                Cp[off + nt * 16] = (_Float16)acc[mt][nt][rr];
        }
}

// ---------------- K2: finalize BN stats into affine coefs -----------------------
__global__ __launch_bounds__(256) void stats_kernel(const float* __restrict__ sums,
                                                    const float* __restrict__ sumsq,
                                                    const float* __restrict__ bnw,
                                                    const float* __restrict__ bnb,
                                                    float* __restrict__ cA,
                                                    float* __restrict__ cB) {
    int i = blockIdx.x * 256 + threadIdx.x;    // 0..4095
    float mean = sums[i] * (1.0f / Nn);
    float var  = sumsq[i] * (1.0f / Nn) - mean * mean;
    float inv  = rsqrtf(var + BN_EPS_);
    float a    = bnw[i] * inv;
    cA[i] = a;
    cB[i] = bnb[i] - mean * a;
}

// ---------------- K3: per-row head scan: sparsemax (Michelot, max-seeded) -------
// 256 threads = 4 waves, each wave owns one row n. The sparsemax threshold
// satisfies max(z)-1 <= tau* < max(z), so seeding Michelot at tau0 = max-1
// starts from the few elements within 1.0 of the max (worst-case-bounded).
__global__ __launch_bounds__(256) void rows_kernel(const float* __restrict__ x,
                                                   const _Float16* __restrict__ lg,
                                                   const float* __restrict__ cA,
                                                   const float* __restrict__ cB,
                                                   float* __restrict__ out) {
    const int n    = blockIdx.x * 4 + (threadIdx.x >> 6);
    const int lane = threadIdx.x & 63;
    const int e0   = lane * 4;                 // first chunk; second at +256
    const int bb   = n >> 9;                   // n / Tt
    const int tt   = n & 511;                  // n % Tt

    float xr[8], prior[8];
    {
        const float* xp = x + (size_t)n * Ee;
        float4 x0 = *(const float4*)(xp + e0);
        float4 x1 = *(const float4*)(xp + 256 + e0);
        xr[0]=x0.x; xr[1]=x0.y; xr[2]=x0.z; xr[3]=x0.w;
        xr[4]=x1.x; xr[5]=x1.y; xr[6]=x1.z; xr[7]=x1.w;
    }
#pragma unroll
    for (int j = 0; j < 8; ++j) prior[j] = 1.0f;

    float* omx = out;                               // (H,B,T,E) flat = (H,N,E)
    float* omk = out + (size_t)Hh * Nn * Ee;        // (B,H,T,E)

    const _Float16* lrow = lg + (size_t)n * Ee;
    f16x4 l0 = *(const f16x4*)(lrow + e0);
    f16x4 l1 = *(const f16x4*)(lrow + 256 + e0);

#pragma unroll 1
    for (int h = 0; h < Hh; ++h) {
        // depth-1 prefetch of next head's logits (independent of prior chain)
        f16x4 p0 = l0, p1 = l1;
        if (h + 1 < Hh) {
            const _Float16* lnx = lrow + (size_t)(h + 1) * Nn * Ee;
            p0 = *(const f16x4*)(lnx + e0);
            p1 = *(const f16x4*)(lnx + 256 + e0);
        }
        float z[8];
        {
            const float* ap = cA + h * Ee + e0;
            const float* bp = cB + h * Ee + e0;
            float4 a0 = *(const float4*)(ap);
            float4 b0 = *(const float4*)(bp);
            float4 a1 = *(const float4*)(ap + 256);
            float4 b1 = *(const float4*)(bp + 256);
            z[0] = ((float)l0[0] * a0.x + b0.x) * prior[0];
            z[1] = ((float)l0[1] * a0.y + b0.y) * prior[1];
            z[2] = ((float)l0[2] * a0.z + b0.z) * prior[2];
            z[3] = ((float)l0[3] * a0.w + b0.w) * prior[3];
            z[4] = ((float)l1[0] * a1.x + b1.x) * prior[4];
            z[5] = ((float)l1[1] * a1.y + b1.y) * prior[5];
            z[6] = ((float)l1[2] * a1.z + b1.z) * prior[6];
            z[7] = ((float)l1[3] * a1.w + b1.w) * prior[7];
        }

        // Michelot seeded at tau0 = max - 1 (exact sparsemax threshold).
        float mx = z[0];
#pragma unroll
        for (int j = 1; j < 8; ++j) mx = fmaxf(mx, z[j]);
        float tau = dpp_max64(mx) - 1.0f;
        int cprev = -1;
#pragma unroll 1
        for (int it = 0; it < 64; ++it) {
            float s2 = 0.f;
            int cnt = 0;
#pragma unroll
            for (int j = 0; j < 8; ++j) {
                bool p = z[j] > tau;
                s2 += p ? z[j] : 0.0f;
                cnt += (int)__popcll(__ballot(p));
            }
            float S = dpp_sum64(s2);
            if (cnt == cprev) break;
            cprev = cnt;
            tau = (S - 1.0f) / (float)cnt;
        }

        size_t oxoff = ((size_t)h * Nn + n) * Ee + e0;
        size_t okoff = (((size_t)bb * Hh + h) * Tt + tt) * Ee + e0;
        f32x4 vx, vm;
#pragma unroll
        for (int j = 0; j < 4; ++j) {
            float m = fmaxf(z[j] - tau, 0.0f);
            prior[j] *= fmaxf(GAMMA_ - m, 0.0f);
            vm[j] = m; vx[j] = xr[j] * m;
        }
        __builtin_nontemporal_store(vx, (f32x4*)(omx + oxoff));
        __builtin_nontemporal_store(vm, (f32x4*)(omk + okoff));
#pragma unroll
        for (int j = 0; j < 4; ++j) {
            float m = fmaxf(z[4 + j] - tau, 0.0f);
            prior[4 + j] *= fmaxf(GAMMA_ - m, 0.0f);
            vm[j] = m; vx[j] = xr[4 + j] * m;
        }
        __builtin_nontemporal_store(vx, (f32x4*)(omx + oxoff + 256));
        __builtin_nontemporal_store(vm, (f32x4*)(omk + okoff + 256));
        l0 = p0; l1 = p1;
    }
}

extern "C" void kernel_launch(void* const* d_in, const int* in_sizes, int n_in,
                              void* d_out, int out_size, void* d_ws, size_t ws_size,
                              hipStream_t stream) {
    const float* x   = (const float*)d_in[0];
    const float* W   = (const float*)d_in[1];
    const float* bnw = (const float*)d_in[2];
    const float* bnb = (const float*)d_in[3];
    float* out = (float*)d_out;

    uint8_t* ws = (uint8_t*)d_ws;
    _Float16* xh = (_Float16*)(ws);                    // 16,777,216 B
    _Float16* wh = (_Float16*)(ws + 16777216);         //  4,194,304 B
    _Float16* lg = (_Float16*)(ws + 20971520);         // 134,217,728 B
    float* sums  = (float*)(ws + 155189248);           // 16,384 B
    float* sumsq = (float*)(ws + 155205632);           // 16,384 B
    float* cA    = (float*)(ws + 155222016);           // 16,384 B
    float* cB    = (float*)(ws + 155238400);           // 16,384 B (total ~148 MB)

    cvt_kernel<<<10240, 256, 0, stream>>>(x, W, xh, wh, sums);   // also zeros sums+sumsq
    gemm_kernel<<<1024, 512, 0, stream>>>(xh, wh, lg, sums, sumsq);
    stats_kernel<<<16, 256, 0, stream>>>(sums, sumsq, bnw, bnb, cA, cB);
    rows_kernel<<<4096, 256, 0, stream>>>(x, lg, cA, cB, out);
}

// Round 8
// 645.080 us; speedup vs baseline: 1.0333x; 1.0019x over previous
//
#include <hip/hip_runtime.h>
#include <stdint.h>

#define Hh 8
#define Bb 32
#define Tt 512
#define Ee 512
#define Nn 16384            // Bb*Tt
#define GAMMA_ 1.5f
#define BN_EPS_ 1e-5f

typedef _Float16 f16x4 __attribute__((ext_vector_type(4)));
typedef _Float16 f16x8 __attribute__((ext_vector_type(8)));
typedef float    f32x4 __attribute__((ext_vector_type(4)));

__device__ __forceinline__ void async_ld16(void* lds, const void* g) {
    __builtin_amdgcn_global_load_lds(
        (const __attribute__((address_space(1))) void*)g,
        (__attribute__((address_space(3))) void*)lds, 16, 0, 0);
}

// Full-wave (64-lane) f32 sum via DPP (pure VALU, no DS pipe).
__device__ __forceinline__ float dpp_sum64(float v) {
    int t;
    t = __builtin_amdgcn_update_dpp(0, __float_as_int(v), 0x111, 0xf, 0xf, true);
    v += __int_as_float(t);
    t = __builtin_amdgcn_update_dpp(0, __float_as_int(v), 0x112, 0xf, 0xf, true);
    v += __int_as_float(t);
    t = __builtin_amdgcn_update_dpp(0, __float_as_int(v), 0x114, 0xf, 0xf, true);
    v += __int_as_float(t);
    t = __builtin_amdgcn_update_dpp(0, __float_as_int(v), 0x118, 0xf, 0xf, true);
    v += __int_as_float(t);
    t = __builtin_amdgcn_update_dpp(0, __float_as_int(v), 0x142, 0xf, 0xf, true);
    v += __int_as_float(t);
    t = __builtin_amdgcn_update_dpp(0, __float_as_int(v), 0x143, 0xf, 0xf, true);
    v += __int_as_float(t);
    return __int_as_float(__builtin_amdgcn_readlane(__float_as_int(v), 63));
}

// Full-wave f32 max via DPP. old=src + bound_ctrl=false => invalid lanes are
// identity under fmax (no 0.0 injection; safe for all-negative inputs).
__device__ __forceinline__ float dpp_max64(float v) {
    int t;
    t = __builtin_amdgcn_update_dpp(__float_as_int(v), __float_as_int(v), 0x111, 0xf, 0xf, false);
    v = fmaxf(v, __int_as_float(t));
    t = __builtin_amdgcn_update_dpp(__float_as_int(v), __float_as_int(v), 0x112, 0xf, 0xf, false);
    v = fmaxf(v, __int_as_float(t));
    t = __builtin_amdgcn_update_dpp(__float_as_int(v), __float_as_int(v), 0x114, 0xf, 0xf, false);
    v = fmaxf(v, __int_as_float(t));
    t = __builtin_amdgcn_update_dpp(__float_as_int(v), __float_as_int(v), 0x118, 0xf, 0xf, false);
    v = fmaxf(v, __int_as_float(t));
    t = __builtin_amdgcn_update_dpp(__float_as_int(v), __float_as_int(v), 0x142, 0xf, 0xf, false);
    v = fmaxf(v, __int_as_float(t));
    t = __builtin_amdgcn_update_dpp(__float_as_int(v), __float_as_int(v), 0x143, 0xf, 0xf, false);
    v = fmaxf(v, __int_as_float(t));
    return __int_as_float(__builtin_amdgcn_readlane(__float_as_int(v), 63));
}

// ---------------- K0: fp32 -> f16 convert (x then W) + zero BN accumulators -----
__global__ __launch_bounds__(256) void cvt_kernel(const float* __restrict__ x,
                                                  const float* __restrict__ W,
                                                  _Float16* __restrict__ xh,
                                                  _Float16* __restrict__ wh,
                                                  float* __restrict__ sums) {
    const int NX = Bb * Tt * Ee;               // 8388608, divisible by 4
    const int tid_g = blockIdx.x * 256 + threadIdx.x;   // 0..2621439
    int i = tid_g * 4;
    if (i < NX) {
        float4 v = *(const float4*)(x + i);
        f16x4 o = {(_Float16)v.x, (_Float16)v.y, (_Float16)v.z, (_Float16)v.w};
        *(f16x4*)(xh + i) = o;
    } else {
        int j = i - NX;                        // 0 .. 2097151
        float4 v = *(const float4*)(W + j);
        f16x4 o = {(_Float16)v.x, (_Float16)v.y, (_Float16)v.z, (_Float16)v.w};
        *(f16x4*)(wh + j) = o;
    }
    int zi = tid_g - (2621440 - 2048);         // last 2048 threads
    if (zi >= 0) {
        float4 zz = {0.f, 0.f, 0.f, 0.f};
        ((float4*)sums)[zi] = zz;              // sums+sumsq contiguous, 32 KB
    }
}

// ---------------- K1: batched NT GEMM, 256x256, BK=64, 8-phase counted-vmcnt ----
// R7 failed with A-quadrant race: waves read A quadrants {q0,q2} at ph0/ph1
// (mt0-3: rows 0-63 & 128-191) and {q1,q3} at ph2/ph3 -- R7 staged {q0,q1} at
// ph2, clobbering q1 mid-read. Corrected stage stream (A halves = {q0,q2} and
// {q1,q3}; B is fully consumed into regs by ph1-end so B stages at ph2/ph3):
//   prologue: tile0 full (8) + T1 A q0,q2 + B q0-3 (6)
//   ph0: T1 A q1,q3 -> buf1   (prev occupant's q1,q3 reads ended at ph6/ph7)
//   ph2: T2 A q0,q2 + B q0,q1 -> buf0   (free since ph1-end)
//   ph3: T2 B q2,q3; boundary wait vmcnt(6) retires T1's 8 exactly
//   ph4: T2 A q1,q3 -> buf0   (free since ph3-end)
//   ph6: T3 A q0,q2 + B q0,q1 -> buf1; ph7: T3 B q2,q3; wait vmcnt(6)
// In-flight ledger: boundary = 8(T1)+6(T2)=14, vmcnt(6) retires oldest 8 ✓;
// steady-state identical each half-iteration; vmcnt(0) only at the last tile.
// Every stage is issued after the barrier closing the last read of its
// destination quadrant (WAR barrier-protected). Raw s_barrier, compiler
// lgkmcnt for ds_read->MFMA, setprio(1) per MFMA cluster (T5).
__global__ __launch_bounds__(512, 2) void gemm_kernel(const _Float16* __restrict__ A,
                                                      const _Float16* __restrict__ Bm,
                                                      _Float16* __restrict__ C,
                                                      float* __restrict__ sums,
                                                      float* __restrict__ sumsq) {
    __shared__ alignas(16) _Float16 As[2][256 * 64];   // 2 x 32 KB
    __shared__ alignas(16) _Float16 Bs[2][256 * 64];   // 2 x 32 KB
    // XCD-aware swizzle: 1024 blocks, 8 XCDs, 128 blocks (one head) per XCD.
    const int id  = (blockIdx.x & 7) * 128 + (blockIdx.x >> 3);
    const int h   = id >> 7;
    const int rem = id & 127;
    const int mb  = (rem >> 1) * 256;          // 64 row-blocks
    const int nb  = (rem & 1) * 256;           // 2 col-blocks

    const int t    = threadIdx.x;              // 0..511
    const int lane = t & 63;
    const int w    = t >> 6;                   // 0..7
    const int wrow = (w >> 2) * 128;           // 0,128
    const int wcol = (w & 3) * 64;             // 0,64,128,192
    const int quad = lane >> 4;
    const int l16  = lane & 15;

    // staging: thread t covers row (t>>3)+q*64, chunk slot t&7; global k-chunk
    // c = (slot - (row>>1)) & 7 (R4-verified). LDS index = q*4096 + t*8.
    const int c = ((t & 7) - ((t >> 4) & 7)) & 7;
    const _Float16* Ap = A + (size_t)(mb + (t >> 3)) * Ee + c * 8;
    const _Float16* Bp = Bm + (size_t)h * Ee * Ee + (size_t)(nb + (t >> 3)) * Ee + c * 8;

#define STG_A(b, q, tt) async_ld16(&As[b][(q) * 4096 + t * 8], Ap + (tt) * 64 + (q) * 64 * Ee)
#define STG_B(b, q, tt) async_ld16(&Bs[b][(q) * 4096 + t * 8], Bp + (tt) * 64 + (q) * 64 * Ee)
#define BAR() do { asm volatile("" ::: "memory"); __builtin_amdgcn_s_barrier(); \
                   asm volatile("" ::: "memory"); } while (0)

    f32x4 acc[8][4] = {};
    f16x8 a8[4], b8[2][4];

    auto rdA = [&](int bsel, int mt, int kk) {
        int row = wrow + mt * 16 + l16;
        int sl  = ((kk * 4 + quad) + ((row >> 1) & 7)) & 7;
        return *(const f16x8*)(&As[bsel][row * 64 + sl * 8]);
    };
    auto rdB = [&](int bsel, int nt, int kk) {
        int row = wcol + nt * 16 + l16;
        int sl  = ((kk * 4 + quad) + ((row >> 1) & 7)) & 7;
        return *(const f16x8*)(&Bs[bsel][row * 64 + sl * 8]);
    };
    auto mm = [&](int mh, int kk) {
        __builtin_amdgcn_s_setprio(1);
#pragma unroll
        for (int j = 0; j < 4; ++j)
#pragma unroll
            for (int nt = 0; nt < 4; ++nt)
                acc[mh * 4 + j][nt] = __builtin_amdgcn_mfma_f32_16x16x32_f16(
                    a8[j], b8[kk][nt], acc[mh * 4 + j][nt], 0, 0, 0);
        __builtin_amdgcn_s_setprio(0);
    };

    // prologue: tile0 full (8 loads) + tile1 partial A q0,q2 + B q0-3 (6 loads)
#pragma unroll
    for (int q = 0; q < 4; ++q) { STG_A(0, q, 0); STG_B(0, q, 0); }
    STG_A(1, 0, 1); STG_A(1, 2, 1);
    STG_B(1, 0, 1); STG_B(1, 1, 1); STG_B(1, 2, 1); STG_B(1, 3, 1);
    asm volatile("s_waitcnt vmcnt(6)" ::: "memory");   // retire tile0's 8
    BAR();

#pragma unroll 1
    for (int i = 0; i < 4; ++i) {
        const int T1 = 2 * i + 1;
        const int T2 = 2 * i + 2;              // next even tile -> buf0
        const int T3 = 2 * i + 3;              // next odd tile  -> buf1
        const bool st = (i < 3);

        // ph0: buf0 kk0 mt0-3 (A q0,q2) + B kk0; stage T1 A q1,q3 -> buf1
#pragma unroll
        for (int nt = 0; nt < 4; ++nt) b8[0][nt] = rdB(0, nt, 0);
#pragma unroll
        for (int j = 0; j < 4; ++j) a8[j] = rdA(0, j, 0);
        STG_A(1, 1, T1); STG_A(1, 3, T1);
        BAR();
        mm(0, 0);
        BAR();

        // ph1: buf0 kk1 mt0-3 + B kk1
#pragma unroll
        for (int nt = 0; nt < 4; ++nt) b8[1][nt] = rdB(0, nt, 1);
#pragma unroll
        for (int j = 0; j < 4; ++j) a8[j] = rdA(0, j, 1);
        BAR();
        mm(0, 1);
        BAR();

        // ph2: buf0 kk0 mt4-7 (A q1,q3; B from regs); stage T2 A q0,q2 + B q0,q1
#pragma unroll
        for (int j = 0; j < 4; ++j) a8[j] = rdA(0, 4 + j, 0);
        if (st) { STG_A(0, 0, T2); STG_A(0, 2, T2); STG_B(0, 0, T2); STG_B(0, 1, T2); }
        BAR();
        mm(1, 0);
        BAR();

        // ph3: buf0 kk1 mt4-7; stage T2 B q2,q3; K-tile boundary wait
#pragma unroll
        for (int j = 0; j < 4; ++j) a8[j] = rdA(0, 4 + j, 1);
        if (st) { STG_B(0, 2, T2); STG_B(0, 3, T2); }
        BAR();
        mm(1, 1);
        if (st) asm volatile("s_waitcnt vmcnt(6)" ::: "memory");  // retire T1's 8
        else    asm volatile("s_waitcnt vmcnt(0)" ::: "memory");  // last tile
        BAR();

        // ph4: buf1 kk0 mt0-3 + B kk0; stage T2 A q1,q3 -> buf0
#pragma unroll
        for (int nt = 0; nt < 4; ++nt) b8[0][nt] = rdB(1, nt, 0);
#pragma unroll
        for (int j = 0; j < 4; ++j) a8[j] = rdA(1, j, 0);
        if (st) { STG_A(0, 1, T2); STG_A(0, 3, T2); }
        BAR();
        mm(0, 0);
        BAR();

        // ph5: buf1 kk1 mt0-3 + B kk1
#pragma unroll
        for (int nt = 0; nt < 4; ++nt) b8[1][nt] = rdB(1, nt, 1);
#pragma unroll
        for (int j = 0; j < 4; ++j) a8[j] = rdA(1, j, 1);
        BAR();
        mm(0, 1);
        BAR();

        // ph6: buf1 kk0 mt4-7; stage T3 A q0,q2 + B q0,q1 -> buf1
#pragma unroll
        for (int j = 0; j < 4; ++j) a8[j] = rdA(1, 4 + j, 0);
        if (st) { STG_A(1, 0, T3); STG_A(1, 2, T3); STG_B(1, 0, T3); STG_B(1, 1, T3); }
        BAR();
        mm(1, 0);
        BAR();

        // ph7: buf1 kk1 mt4-7; stage T3 B q2,q3; K-tile boundary wait
#pragma unroll
        for (int j = 0; j < 4; ++j) a8[j] = rdA(1, 4 + j, 1);
        if (st) { STG_B(1, 2, T3); STG_B(1, 3, T3); }
        BAR();
        mm(1, 1);
        if (st) {
            asm volatile("s_waitcnt vmcnt(6)" ::: "memory");      // retire T2's 8
            BAR();
        }
    }
#undef STG_A
#undef STG_B
#undef BAR

    // BN partial sums: reduce over rows (mt,r) then across quads (lanes xor 16,32)
#pragma unroll
    for (int nt = 0; nt < 4; ++nt) {
        float sv = 0.f, ss = 0.f;
#pragma unroll
        for (int mt = 0; mt < 8; ++mt)
#pragma unroll
            for (int rr = 0; rr < 4; ++rr) { float v = acc[mt][nt][rr]; sv += v; ss += v * v; }
        sv += __shfl_xor(sv, 16, 64); sv += __shfl_xor(sv, 32, 64);
        ss += __shfl_xor(ss, 16, 64); ss += __shfl_xor(ss, 32, 64);
        if (quad == 0) {
            int col = nb + wcol + nt * 16 + l16;
            atomicAdd(&sums[h * Ee + col], sv);
            atomicAdd(&sumsq[h * Ee + col], ss);
        }
    }

    // store C (f16): C/D layout col=lane&15, row=quad*4+reg
    _Float16* Cp = C + (size_t)h * Nn * Ee;
#pragma unroll
    for (int mt = 0; mt < 8; ++mt)
#pragma unroll
        for (int rr = 0; rr < 4; ++rr) {
            int row = mb + wrow + mt * 16 + quad * 4 + rr;
            size_t off = (size_t)row * Ee + nb + wcol + l16;
#pragma unroll
            for (int nt = 0; nt < 4; ++nt)
                Cp[off + nt * 16] = (_Float16)acc[mt][nt][rr];
        }
}

// ---------------- K2: finalize BN stats into affine coefs -----------------------
__global__ __launch_bounds__(256) void stats_kernel(const float* __restrict__ sums,
                                                    const float* __restrict__ sumsq,
                                                    const float* __restrict__ bnw,
                                                    const float* __restrict__ bnb,
                                                    float* __restrict__ cA,
                                                    float* __restrict__ cB) {
    int i = blockIdx.x * 256 + threadIdx.x;    // 0..4095
    float mean = sums[i] * (1.0f / Nn);
    float var  = sumsq[i] * (1.0f / Nn) - mean * mean;
    float inv  = rsqrtf(var + BN_EPS_);
    float a    = bnw[i] * inv;
    cA[i] = a;
    cB[i] = bnb[i] - mean * a;
}

// ---------------- K3: per-row head scan: sparsemax (Michelot, max-seeded) -------
// 256 threads = 4 waves, each wave owns one row n. The sparsemax threshold
// satisfies max(z)-1 <= tau* < max(z), so seeding Michelot at tau0 = max-1
// starts from the few elements within 1.0 of the max (worst-case-bounded).
__global__ __launch_bounds__(256) void rows_kernel(const float* __restrict__ x,
                                                   const _Float16* __restrict__ lg,
                                                   const float* __restrict__ cA,
                                                   const float* __restrict__ cB,
                                                   float* __restrict__ out) {
    const int n    = blockIdx.x * 4 + (threadIdx.x >> 6);
    const int lane = threadIdx.x & 63;
    const int e0   = lane * 4;                 // first chunk; second at +256
    const int bb   = n >> 9;                   // n / Tt
    const int tt   = n & 511;                  // n % Tt

    float xr[8], prior[8];
    {
        const float* xp = x + (size_t)n * Ee;
        float4 x0 = *(const float4*)(xp + e0);
        float4 x1 = *(const float4*)(xp + 256 + e0);
        xr[0]=x0.x; xr[1]=x0.y; xr[2]=x0.z; xr[3]=x0.w;
        xr[4]=x1.x; xr[5]=x1.y; xr[6]=x1.z; xr[7]=x1.w;
    }
#pragma unroll
    for (int j = 0; j < 8; ++j) prior[j] = 1.0f;

    float* omx = out;                               // (H,B,T,E) flat = (H,N,E)
    float* omk = out + (size_t)Hh * Nn * Ee;        // (B,H,T,E)

    const _Float16* lrow = lg + (size_t)n * Ee;
    f16x4 l0 = *(const f16x4*)(lrow + e0);
    f16x4 l1 = *(const f16x4*)(lrow + 256 + e0);

#pragma unroll 1
    for (int h = 0; h < Hh; ++h) {
        // depth-1 prefetch of next head's logits (independent of prior chain)
        f16x4 p0 = l0, p1 = l1;
        if (h + 1 < Hh) {
            const _Float16* lnx = lrow + (size_t)(h + 1) * Nn * Ee;
            p0 = *(const f16x4*)(lnx + e0);
            p1 = *(const f16x4*)(lnx + 256 + e0);
        }
        float z[8];
        {
            const float* ap = cA + h * Ee + e0;
            const float* bp = cB + h * Ee + e0;
            float4 a0 = *(const float4*)(ap);
            float4 b0 = *(const float4*)(bp);
            float4 a1 = *(const float4*)(ap + 256);
            float4 b1 = *(const float4*)(bp + 256);
            z[0] = ((float)l0[0] * a0.x + b0.x) * prior[0];
            z[1] = ((float)l0[1] * a0.y + b0.y) * prior[1];
            z[2] = ((float)l0[2] * a0.z + b0.z) * prior[2];
            z[3] = ((float)l0[3] * a0.w + b0.w) * prior[3];
            z[4] = ((float)l1[0] * a1.x + b1.x) * prior[4];
            z[5] = ((float)l1[1] * a1.y + b1.y) * prior[5];
            z[6] = ((float)l1[2] * a1.z + b1.z) * prior[6];
            z[7] = ((float)l1[3] * a1.w + b1.w) * prior[7];
        }

        // Michelot seeded at tau0 = max - 1 (exact sparsemax threshold).
        float mx = z[0];
#pragma unroll
        for (int j = 1; j < 8; ++j) mx = fmaxf(mx, z[j]);
        float tau = dpp_max64(mx) - 1.0f;
        int cprev = -1;
#pragma unroll 1
        for (int it = 0; it < 64; ++it) {
            float s2 = 0.f;
            int cnt = 0;
#pragma unroll
            for (int j = 0; j < 8; ++j) {
                bool p = z[j] > tau;
                s2 += p ? z[j] : 0.0f;
                cnt += (int)__popcll(__ballot(p));
            }
            float S = dpp_sum64(s2);
            if (cnt == cprev) break;
            cprev = cnt;
            tau = (S - 1.0f) / (float)cnt;
        }

        size_t oxoff = ((size_t)h * Nn + n) * Ee + e0;
        size_t okoff = (((size_t)bb * Hh + h) * Tt + tt) * Ee + e0;
        f32x4 vx, vm;
#pragma unroll
        for (int j = 0; j < 4; ++j) {
            float m = fmaxf(z[j] - tau, 0.0f);
            prior[j] *= fmaxf(GAMMA_ - m, 0.0f);
            vm[j] = m; vx[j] = xr[j] * m;
        }
        __builtin_nontemporal_store(vx, (f32x4*)(omx + oxoff));
        __builtin_nontemporal_store(vm, (f32x4*)(omk + okoff));
#pragma unroll
        for (int j = 0; j < 4; ++j) {
            float m = fmaxf(z[4 + j] - tau, 0.0f);
            prior[4 + j] *= fmaxf(GAMMA_ - m, 0.0f);
            vm[j] = m; vx[j] = xr[4 + j] * m;
        }
        __builtin_nontemporal_store(vx, (f32x4*)(omx + oxoff + 256));
        __builtin_nontemporal_store(vm, (f32x4*)(omk + okoff + 256));
        l0 = p0; l1 = p1;
    }
}

extern "C" void kernel_launch(void* const* d_in, const int* in_sizes, int n_in,
                              void* d_out, int out_size, void* d_ws, size_t ws_size,
                              hipStream_t stream) {
    const float* x   = (const float*)d_in[0];
    const float* W   = (const float*)d_in[1];
    const float* bnw = (const float*)d_in[2];
    const float* bnb = (const float*)d_in[3];
    float* out = (float*)d_out;

    uint8_t* ws = (uint8_t*)d_ws;
    _Float16* xh = (_Float16*)(ws);                    // 16,777,216 B
    _Float16* wh = (_Float16*)(ws + 16777216);         //  4,194,304 B
    _Float16* lg = (_Float16*)(ws + 20971520);         // 134,217,728 B
    float* sums  = (float*)(ws + 155189248);           // 16,384 B
    float* sumsq = (float*)(ws + 155205632);           // 16,384 B
    float* cA    = (float*)(ws + 155222016);           // 16,384 B
    float* cB    = (float*)(ws + 155238400);           // 16,384 B (total ~148 MB)

    cvt_kernel<<<10240, 256, 0, stream>>>(x, W, xh, wh, sums);   // also zeros sums+sumsq
    gemm_kernel<<<1024, 512, 0, stream>>>(xh, wh, lg, sums, sumsq);
    stats_kernel<<<16, 256, 0, stream>>>(sums, sumsq, bnw, bnb, cA, cB);
    rows_kernel<<<4096, 256, 0, stream>>>(x, lg, cA, cB, out);
}